// Round 1
// baseline (1126.262 us; speedup 1.0000x reference)
//
#include <hip/hip_runtime.h>
#include <hip/hip_bf16.h>

// Problem dims (fixed)
#define NROWS 8192   // N == M == 8192
#define DIM   512    // IN_FEATS == OUT_FEATS == 512

typedef short v8s __attribute__((ext_vector_type(8)));
typedef short v4s __attribute__((ext_vector_type(4)));
typedef float v4f __attribute__((ext_vector_type(4)));

__device__ __forceinline__ short f2bf(float f) {
    union { float f; unsigned u; } v; v.f = f;
    unsigned r = (v.u + 0x7fffu + ((v.u >> 16) & 1u)) >> 16;
    return (short)r;
}

// ---------------------------------------------------------------------------
// Cast f32 [R][C] -> bf16 transposed [C][R]
// grid (R/32, C/32), block 256
// ---------------------------------------------------------------------------
__global__ __launch_bounds__(256) void transpose_cast_kernel(
        const float* __restrict__ in, short* __restrict__ out, int R, int C) {
    __shared__ float t[32][33];
    const int lx = threadIdx.x & 31;
    const int ly = threadIdx.x >> 5;  // 0..7
    const int r0 = blockIdx.x * 32;
    const int c0 = blockIdx.y * 32;
#pragma unroll
    for (int p = 0; p < 4; ++p)
        t[ly + 8 * p][lx] = in[(size_t)(r0 + ly + 8 * p) * C + c0 + lx];
    __syncthreads();
#pragma unroll
    for (int p = 0; p < 4; ++p)
        out[(size_t)(c0 + ly + 8 * p) * R + r0 + lx] = f2bf(t[lx][ly + 8 * p]);
}

// ---------------------------------------------------------------------------
// H = cast_bf16(F) @ W   using WT (bf16, [DIM out][DIM k]) ; H bf16 [NROWS][DIM]
// grid (NROWS/64, DIM/64), block 256 (4 waves); wave w -> rows 16w..16w+16
// ---------------------------------------------------------------------------
__global__ __launch_bounds__(256) void gemm1_kernel(
        const float* __restrict__ F, const short* __restrict__ WT,
        short* __restrict__ H) {
    const int lane = threadIdx.x & 63;
    const int wid  = threadIdx.x >> 6;
    const int lr = lane & 15, lg = lane >> 4;
    const int r0 = blockIdx.x * 64 + wid * 16;
    const int c0 = blockIdx.y * 64;

    v4f acc[4] = {};
#pragma unroll
    for (int kc = 0; kc < 16; ++kc) {
        const int k = kc * 32 + lg * 8;
        const float* ap = F + (size_t)(r0 + lr) * DIM + k;
        float4 f0 = *(const float4*)ap;
        float4 f1 = *(const float4*)(ap + 4);
        v8s a;
        a[0] = f2bf(f0.x); a[1] = f2bf(f0.y); a[2] = f2bf(f0.z); a[3] = f2bf(f0.w);
        a[4] = f2bf(f1.x); a[5] = f2bf(f1.y); a[6] = f2bf(f1.z); a[7] = f2bf(f1.w);
#pragma unroll
        for (int ct = 0; ct < 4; ++ct) {
            v8s b = *(const v8s*)(WT + (size_t)(c0 + ct * 16 + lr) * DIM + k);
            acc[ct] = __builtin_amdgcn_mfma_f32_16x16x32_bf16(a, b, acc[ct], 0, 0, 0);
        }
    }
#pragma unroll
    for (int ct = 0; ct < 4; ++ct)
#pragma unroll
        for (int i = 0; i < 4; ++i)
            H[(size_t)(r0 + lg * 4 + i) * DIM + c0 + ct * 16 + lr] = f2bf(acc[ct][i]);
}

// ---------------------------------------------------------------------------
// Fused: for a 64-row tile of Hp and a j-range, accumulate
//   C[tile] += relu(Hp_tile @ Hs^T) @ Fs    and   ssq += sum(relu(.)^2)
// grid (NROWS/64, JSPLIT), block 512 (8 waves)
//   wave w: strip = w>>1 (16 rows), half = w&1 (phase A: S-cols 32*half..;
//                                   phase B: C-cols 256*half..)
// ---------------------------------------------------------------------------
#define JSPLIT 4
#define JT_PER_BLOCK (NROWS / 64 / JSPLIT)   // 32 j-tiles of 64

__global__ __launch_bounds__(512) void fused_kernel(
        const short* __restrict__ Hp, const short* __restrict__ Hs,
        const short* __restrict__ FsT, float* __restrict__ Cacc,
        float* __restrict__ ssq) {
    __shared__ short Sb[64][72];   // 64x64 bf16 S-tile, +8 pad (2-way banks = free)

    const int lane = threadIdx.x & 63;
    const int wid  = threadIdx.x >> 6;     // 0..7
    const int lr = lane & 15, lg = lane >> 4;
    const int m0    = blockIdx.x * 64;
    const int strip = wid >> 1;            // 0..3
    const int half  = wid & 1;             // 0..1

    // Hold this wave's 16 Hp rows (full K=512) as A-fragments: 64 VGPRs
    v8s afrag[16];
#pragma unroll
    for (int kc = 0; kc < 16; ++kc)
        afrag[kc] = *(const v8s*)(Hp + (size_t)(m0 + strip * 16 + lr) * DIM + kc * 32 + lg * 8);

    v4f accC[16] = {};
    float ssq_l = 0.f;

    const int jt0 = blockIdx.y * JT_PER_BLOCK;
    for (int jt = jt0; jt < jt0 + JT_PER_BLOCK; ++jt) {
        const int j = jt * 64;
        // ---- phase A: S = Hp_strip @ Hs_tile^T (this wave: 2 16x16 subtiles)
        v4f s0 = {}, s1 = {};
        {
            const size_t b0 = (size_t)(j + (half * 2 + 0) * 16 + lr) * DIM + lg * 8;
            const size_t b1 = (size_t)(j + (half * 2 + 1) * 16 + lr) * DIM + lg * 8;
#pragma unroll
            for (int kc = 0; kc < 16; ++kc) {
                v8s hb0 = *(const v8s*)(Hs + b0 + kc * 32);
                v8s hb1 = *(const v8s*)(Hs + b1 + kc * 32);
                s0 = __builtin_amdgcn_mfma_f32_16x16x32_bf16(afrag[kc], hb0, s0, 0, 0, 0);
                s1 = __builtin_amdgcn_mfma_f32_16x16x32_bf16(afrag[kc], hb1, s1, 0, 0, 0);
            }
        }
        // ---- relu + ssq + bf16 + LDS
        __syncthreads();   // previous iteration's phase-B reads complete
#pragma unroll
        for (int i = 0; i < 4; ++i) {
            float v0 = fmaxf(s0[i], 0.f), v1 = fmaxf(s1[i], 0.f);
            ssq_l += v0 * v0 + v1 * v1;
            const int r = strip * 16 + lg * 4 + i;
            Sb[r][(half * 2 + 0) * 16 + lr] = f2bf(v0);
            Sb[r][(half * 2 + 1) * 16 + lr] = f2bf(v1);
        }
        __syncthreads();   // S-tile visible
        // ---- phase B: C += S_tile @ Fs_tile   (B-frags from FsT rows)
#pragma unroll
        for (int kc2 = 0; kc2 < 2; ++kc2) {
            const short* sp = &Sb[strip * 16 + lr][kc2 * 32 + lg * 8];
            v4s lo = *(const v4s*)sp;
            v4s hi = *(const v4s*)(sp + 4);
            v8s aS = {lo[0], lo[1], lo[2], lo[3], hi[0], hi[1], hi[2], hi[3]};
            const size_t fb = (size_t)j + kc2 * 32 + lg * 8;
#pragma unroll
            for (int ct = 0; ct < 16; ++ct) {
                v8s bF = *(const v8s*)(FsT + (size_t)(half * 256 + ct * 16 + lr) * NROWS + fb);
                accC[ct] = __builtin_amdgcn_mfma_f32_16x16x32_bf16(aS, bF, accC[ct], 0, 0, 0);
            }
        }
    }

    // ---- epilogue: ssq wave-reduce + atomic; C-partials atomicAdd
    float w = ssq_l;
#pragma unroll
    for (int off = 32; off; off >>= 1) w += __shfl_down(w, off);
    if (lane == 0) atomicAdd(ssq, w);

#pragma unroll
    for (int ct = 0; ct < 16; ++ct)
#pragma unroll
        for (int i = 0; i < 4; ++i)
            atomicAdd(&Cacc[(size_t)(m0 + strip * 16 + lg * 4 + i) * DIM + half * 256 + ct * 16 + lr],
                      accC[ct][i]);
}

// ---------------------------------------------------------------------------
// d_out *= 1/sqrt(ssq)
// ---------------------------------------------------------------------------
__global__ __launch_bounds__(256) void scale_kernel(float* __restrict__ C,
                                                    const float* __restrict__ ssq) {
    const float rs = 1.0f / sqrtf(*ssq);
    const size_t i = (size_t)blockIdx.x * blockDim.x + threadIdx.x;
    float4* p = (float4*)C;
    float4 v = p[i];
    v.x *= rs; v.y *= rs; v.z *= rs; v.w *= rs;
    p[i] = v;
}

// ---------------------------------------------------------------------------
extern "C" void kernel_launch(void* const* d_in, const int* in_sizes, int n_in,
                              void* d_out, int out_size, void* d_ws, size_t ws_size,
                              hipStream_t stream) {
    const float* feat_p   = (const float*)d_in[0];
    const float* feat_s   = (const float*)d_in[1];
    const float* weight_a = (const float*)d_in[2];

    // workspace layout (needs ~24.6 MB)
    char* ws = (char*)d_ws;
    float* ssqp = (float*)ws;                                  // 4 B
    short* WT   = (short*)(ws + 512);                          // 512 KB  [DIM][DIM]
    short* Hp   = (short*)(ws + 512 + 524288);                 // 8 MB    [NROWS][DIM]
    short* Hs   = (short*)(ws + 512 + 524288 + 8388608);       // 8 MB
    short* FsT  = (short*)(ws + 512 + 524288 + 16777216);      // 8 MB    [DIM][NROWS]

    // 1) casts / transposes
    transpose_cast_kernel<<<dim3(DIM / 32, DIM / 32), 256, 0, stream>>>(weight_a, WT, DIM, DIM);
    transpose_cast_kernel<<<dim3(NROWS / 32, DIM / 32), 256, 0, stream>>>(feat_s, FsT, NROWS, DIM);

    // 2) H = feat @ W
    gemm1_kernel<<<dim3(NROWS / 64, DIM / 64), 256, 0, stream>>>(feat_p, WT, Hp);
    gemm1_kernel<<<dim3(NROWS / 64, DIM / 64), 256, 0, stream>>>(feat_s, WT, Hs);

    // 3) zero accumulators (d_out is the unnormalized-C accumulator)
    hipMemsetAsync(d_out, 0, (size_t)out_size * sizeof(float), stream);
    hipMemsetAsync(ssqp, 0, sizeof(float), stream);

    // 4) fused relu(Hp Hs^T) @ feat_s  (+ ssq)
    fused_kernel<<<dim3(NROWS / 64, JSPLIT), 512, 0, stream>>>(Hp, Hs, FsT, (float*)d_out, ssqp);

    // 5) global Frobenius normalization
    scale_kernel<<<(out_size / 4 + 255) / 256, 256, 0, stream>>>((float*)d_out, ssqp);
}

// Round 2
// 482.893 us; speedup vs baseline: 2.3323x; 2.3323x over previous
//
#include <hip/hip_runtime.h>
#include <hip/hip_bf16.h>

// Problem dims (fixed)
#define NROWS 8192   // N == M == 8192
#define DIM   512    // IN_FEATS == OUT_FEATS == 512

typedef short v8s __attribute__((ext_vector_type(8)));
typedef short v4s __attribute__((ext_vector_type(4)));
typedef float v4f __attribute__((ext_vector_type(4)));

#define ASM_VMCNT(n) asm volatile("s_waitcnt vmcnt(" #n ")" ::: "memory")
#define ASM_LGKM0    asm volatile("s_waitcnt lgkmcnt(0)" ::: "memory")
#define BAR          __builtin_amdgcn_s_barrier()

__device__ __forceinline__ short f2bf(float f) {
    union { float f; unsigned u; } v; v.f = f;
    unsigned r = (v.u + 0x7fffu + ((v.u >> 16) & 1u)) >> 16;
    return (short)r;
}

__device__ __forceinline__ void stage16(const void* g, void* l) {
    typedef __attribute__((address_space(1))) const unsigned GA;
    typedef __attribute__((address_space(3))) unsigned LA;
    __builtin_amdgcn_global_load_lds((GA*)(const unsigned*)g, (LA*)(unsigned*)l, 16, 0, 0);
}

// ---------------------------------------------------------------------------
// Cast f32 [R][C] -> bf16 transposed [C][R]
// ---------------------------------------------------------------------------
__global__ __launch_bounds__(256) void transpose_cast_kernel(
        const float* __restrict__ in, short* __restrict__ out, int R, int C) {
    __shared__ float t[32][33];
    const int lx = threadIdx.x & 31;
    const int ly = threadIdx.x >> 5;
    const int r0 = blockIdx.x * 32;
    const int c0 = blockIdx.y * 32;
#pragma unroll
    for (int p = 0; p < 4; ++p)
        t[ly + 8 * p][lx] = in[(size_t)(r0 + ly + 8 * p) * C + c0 + lx];
    __syncthreads();
#pragma unroll
    for (int p = 0; p < 4; ++p)
        out[(size_t)(c0 + ly + 8 * p) * R + r0 + lx] = f2bf(t[lx][ly + 8 * p]);
}

// ---------------------------------------------------------------------------
// H = cast_bf16(F) @ W   using WT (bf16, [out][k]) ; H bf16 [NROWS][DIM]
// ---------------------------------------------------------------------------
__global__ __launch_bounds__(256) void gemm1_kernel(
        const float* __restrict__ F, const short* __restrict__ WT,
        short* __restrict__ H) {
    const int lane = threadIdx.x & 63;
    const int wid  = threadIdx.x >> 6;
    const int lr = lane & 15, lg = lane >> 4;
    const int r0 = blockIdx.x * 64 + wid * 16;
    const int c0 = blockIdx.y * 64;

    v4f acc[4] = {};
#pragma unroll
    for (int kc = 0; kc < 16; ++kc) {
        const int k = kc * 32 + lg * 8;
        const float* ap = F + (size_t)(r0 + lr) * DIM + k;
        float4 f0 = *(const float4*)ap;
        float4 f1 = *(const float4*)(ap + 4);
        v8s a;
        a[0] = f2bf(f0.x); a[1] = f2bf(f0.y); a[2] = f2bf(f0.z); a[3] = f2bf(f0.w);
        a[4] = f2bf(f1.x); a[5] = f2bf(f1.y); a[6] = f2bf(f1.z); a[7] = f2bf(f1.w);
#pragma unroll
        for (int ct = 0; ct < 4; ++ct) {
            v8s b = *(const v8s*)(WT + (size_t)(c0 + ct * 16 + lr) * DIM + k);
            acc[ct] = __builtin_amdgcn_mfma_f32_16x16x32_bf16(a, b, acc[ct], 0, 0, 0);
        }
    }
#pragma unroll
    for (int ct = 0; ct < 4; ++ct)
#pragma unroll
        for (int i = 0; i < 4; ++i)
            H[(size_t)(r0 + lg * 4 + i) * DIM + c0 + ct * 16 + lr] = f2bf(acc[ct][i]);
}

// ---------------------------------------------------------------------------
// Fused kernel
// grid (128, JSPLIT), block 512 (8 waves)
// Phase A (S = Hp_tile @ Hs_tile^T): wave (strip=w>>1, half=w&1) computes
//   S[strip*16..+16][half*32..+32]; Hs staged in LDS chunks (64 j x 128 k),
//   double-buffered, XOR-swizzled via pre-swizzled global source.
// Phase B (C += relu(S) @ Fs): wave w owns C cols w*64..+64 (no FsT
//   redundancy); FsT fragments prefetched into regs at jt start.
// ---------------------------------------------------------------------------
#define JSPLIT 4
#define JT_PER_BLOCK (NROWS / 64 / JSPLIT)   // 32 j-tiles of 64

__device__ __forceinline__ void stage_chunk(const short* __restrict__ Hs,
        short* buf, int j0, int cchunk, int wid, int lane) {
#pragma unroll
    for (int s = 0; s < 2; ++s) {
        const int L = ((wid * 2 + s) * 64 + lane) * 16;   // byte offset in 16KB chunk
        const int row = L >> 8;                            // 256B per row (128 bf16)
        const int p = L & 255;
        const int c = p ^ ((row & 7) << 4);                // inverse swizzle (involution)
        const char* g = (const char*)Hs + ((size_t)(j0 + row) << 10) + (cchunk << 8) + c;
        stage16(g, (char*)buf + L);
    }
}

__device__ __forceinline__ void compute_chunk(const short* buf, const v8s* afrag,
        int cchunk, int half, int lr, int lg, v4f& s0, v4f& s1) {
    const int xo = (lr & 7) << 4;   // swizzle term (rows half*32+lr, +16+lr share lr&7)
#pragma unroll
    for (int kc = 0; kc < 4; ++kc) {
        const int col = kc * 64 + lg * 16;                // bytes within row
        const int r0 = half * 32 + lr;
        v8s hb0 = *(const v8s*)((const char*)buf + r0 * 256 + (col ^ xo));
        v8s hb1 = *(const v8s*)((const char*)buf + (r0 + 16) * 256 + (col ^ xo));
        s0 = __builtin_amdgcn_mfma_f32_16x16x32_bf16(afrag[cchunk * 4 + kc], hb0, s0, 0, 0, 0);
        s1 = __builtin_amdgcn_mfma_f32_16x16x32_bf16(afrag[cchunk * 4 + kc], hb1, s1, 0, 0, 0);
    }
}

__global__ __launch_bounds__(512, 2) void fused_kernel(
        const short* __restrict__ Hp, const short* __restrict__ Hs,
        const short* __restrict__ FsT, float* __restrict__ Cacc,
        float* __restrict__ ssq) {
    __shared__ __align__(16) short HsL[2][64][128];   // 2 x 16KB, swizzled storage
    __shared__ __align__(16) short Sb[64][72];        // S-tile bf16, padded rows (144B)

    const int lane = threadIdx.x & 63;
    const int wid  = threadIdx.x >> 6;
    const int lr = lane & 15, lg = lane >> 4;

    // XCD-aware swizzle: 512 blocks, 8 XCDs -> contiguous chunks of 64
    const int nwg = gridDim.x * gridDim.y;
    const int bid = blockIdx.x + gridDim.x * blockIdx.y;
    const int cpx = nwg >> 3;
    const int swz = (bid & 7) * cpx + (bid >> 3);
    const int bx = swz % gridDim.x;          // 0..127 : m-tile
    const int by = swz / gridDim.x;          // 0..JSPLIT-1 : j-range

    const int m0    = bx * 64;
    const int strip = wid >> 1;
    const int half  = wid & 1;

    // Hp rows for phase A held in registers (64 VGPRs)
    v8s afrag[16];
#pragma unroll
    for (int kc = 0; kc < 16; ++kc)
        afrag[kc] = *(const v8s*)(Hp + (size_t)(m0 + strip * 16 + lr) * DIM + kc * 32 + lg * 8);

    v4f accC[16] = {};
    float ssq_l = 0.f;

    const int jt0 = by * JT_PER_BLOCK;
    stage_chunk(Hs, &HsL[0][0][0], jt0 * 64, 0, wid, lane);   // prologue: chunk0

    for (int jt = jt0; jt < jt0 + JT_PER_BLOCK; ++jt) {
        const int j = jt * 64;

        // prefetch FsT B-fragments for phase B (8 x 16B per lane)
        v8s bF[8];
#pragma unroll
        for (int ct = 0; ct < 4; ++ct)
#pragma unroll
            for (int kc2 = 0; kc2 < 2; ++kc2)
                bF[ct * 2 + kc2] = *(const v8s*)(FsT +
                    (size_t)(wid * 64 + ct * 16 + lr) * NROWS + j + kc2 * 32 + lg * 8);

        v4f s0 = {}, s1 = {};
        // ---- chunk 0 (in HsL[0]) ; stage chunk1 -> HsL[1]
        stage_chunk(Hs, &HsL[1][0][0], j, 1, wid, lane);
        ASM_VMCNT(10); BAR;                       // [2 c0][8 bF][2 c1] -> wait c0
        compute_chunk(&HsL[0][0][0], afrag, 0, half, lr, lg, s0, s1);
        ASM_LGKM0; BAR;
        // ---- chunk 1 ; stage chunk2 -> HsL[0]
        stage_chunk(Hs, &HsL[0][0][0], j, 2, wid, lane);
        ASM_VMCNT(2); BAR;                        // drains bF (long-issued) + c1
        compute_chunk(&HsL[1][0][0], afrag, 1, half, lr, lg, s0, s1);
        ASM_LGKM0; BAR;
        // ---- chunk 2 ; stage chunk3 -> HsL[1]
        stage_chunk(Hs, &HsL[1][0][0], j, 3, wid, lane);
        ASM_VMCNT(2); BAR;
        compute_chunk(&HsL[0][0][0], afrag, 2, half, lr, lg, s0, s1);
        ASM_LGKM0; BAR;
        // ---- chunk 3 ; stage next jt's chunk0 -> HsL[0]
        const int jn = (jt + 1 < jt0 + JT_PER_BLOCK) ? (jt + 1) * 64 : jt0 * 64;
        stage_chunk(Hs, &HsL[0][0][0], jn, 0, wid, lane);
        ASM_VMCNT(2); BAR;
        compute_chunk(&HsL[1][0][0], afrag, 3, half, lr, lg, s0, s1);

        // ---- relu + ssq + S-tile to LDS (bf16)
#pragma unroll
        for (int i = 0; i < 4; ++i) {
            float v0 = fmaxf(s0[i], 0.f), v1 = fmaxf(s1[i], 0.f);
            ssq_l += v0 * v0 + v1 * v1;
            const int r = strip * 16 + lg * 4 + i;
            Sb[r][(half * 2 + 0) * 16 + lr] = f2bf(v0);
            Sb[r][(half * 2 + 1) * 16 + lr] = f2bf(v1);
        }
        ASM_LGKM0; BAR;                           // Sb visible (also drains c3 reads)

        // ---- phase B: C[all rows][wid*64..+64] += S @ Fs
#pragma unroll
        for (int kc2 = 0; kc2 < 2; ++kc2)
#pragma unroll
            for (int mt = 0; mt < 4; ++mt) {
                v8s aS = *(const v8s*)&Sb[mt * 16 + lr][kc2 * 32 + lg * 8];
#pragma unroll
                for (int ct = 0; ct < 4; ++ct)
                    accC[mt * 4 + ct] = __builtin_amdgcn_mfma_f32_16x16x32_bf16(
                        aS, bF[ct * 2 + kc2], accC[mt * 4 + ct], 0, 0, 0);
            }
    }

    // ---- epilogue
    float w = ssq_l;
#pragma unroll
    for (int off = 32; off; off >>= 1) w += __shfl_down(w, off);
    if (lane == 0) atomicAdd(ssq, w);

#pragma unroll
    for (int mt = 0; mt < 4; ++mt)
#pragma unroll
        for (int ct = 0; ct < 4; ++ct)
#pragma unroll
            for (int i = 0; i < 4; ++i)
                atomicAdd(&Cacc[(size_t)(m0 + mt * 16 + lg * 4 + i) * DIM +
                                wid * 64 + ct * 16 + lr],
                          accC[mt * 4 + ct][i]);
}

// ---------------------------------------------------------------------------
__global__ __launch_bounds__(256) void scale_kernel(float* __restrict__ C,
                                                    const float* __restrict__ ssq) {
    const float rs = 1.0f / sqrtf(*ssq);
    const size_t i = (size_t)blockIdx.x * blockDim.x + threadIdx.x;
    float4* p = (float4*)C;
    float4 v = p[i];
    v.x *= rs; v.y *= rs; v.z *= rs; v.w *= rs;
    p[i] = v;
}

// ---------------------------------------------------------------------------
extern "C" void kernel_launch(void* const* d_in, const int* in_sizes, int n_in,
                              void* d_out, int out_size, void* d_ws, size_t ws_size,
                              hipStream_t stream) {
    const float* feat_p   = (const float*)d_in[0];
    const float* feat_s   = (const float*)d_in[1];
    const float* weight_a = (const float*)d_in[2];

    char* ws = (char*)d_ws;
    float* ssqp = (float*)ws;                                  // 4 B
    short* WT   = (short*)(ws + 512);                          // 512 KB
    short* Hp   = (short*)(ws + 512 + 524288);                 // 8 MB
    short* Hs   = (short*)(ws + 512 + 524288 + 8388608);       // 8 MB
    short* FsT  = (short*)(ws + 512 + 524288 + 16777216);      // 8 MB [DIM][NROWS]

    transpose_cast_kernel<<<dim3(DIM / 32, DIM / 32), 256, 0, stream>>>(weight_a, WT, DIM, DIM);
    transpose_cast_kernel<<<dim3(NROWS / 32, DIM / 32), 256, 0, stream>>>(feat_s, FsT, NROWS, DIM);

    gemm1_kernel<<<dim3(NROWS / 64, DIM / 64), 256, 0, stream>>>(feat_p, WT, Hp);
    gemm1_kernel<<<dim3(NROWS / 64, DIM / 64), 256, 0, stream>>>(feat_s, WT, Hs);

    hipMemsetAsync(d_out, 0, (size_t)out_size * sizeof(float), stream);
    hipMemsetAsync(ssqp, 0, sizeof(float), stream);

    fused_kernel<<<dim3(NROWS / 64, JSPLIT), 512, 0, stream>>>(Hp, Hs, FsT, (float*)d_out, ssqp);

    scale_kernel<<<(out_size / 4 + 255) / 256, 256, 0, stream>>>((float*)d_out, ssqp);
}

// Round 3
// 417.094 us; speedup vs baseline: 2.7003x; 1.1578x over previous
//
#include <hip/hip_runtime.h>
#include <hip/hip_bf16.h>

// Problem dims (fixed)
#define NROWS 8192   // N == M == 8192
#define DIM   512    // IN_FEATS == OUT_FEATS == 512

typedef short v8s __attribute__((ext_vector_type(8)));
typedef short v4s __attribute__((ext_vector_type(4)));
typedef float v4f __attribute__((ext_vector_type(4)));

#define ASM_VMCNT(n) asm volatile("s_waitcnt vmcnt(" #n ")" ::: "memory")
#define ASM_LGKM0    asm volatile("s_waitcnt lgkmcnt(0)" ::: "memory")
#define BAR          __builtin_amdgcn_s_barrier()

__device__ __forceinline__ short f2bf(float f) {
    union { float f; unsigned u; } v; v.f = f;
    unsigned r = (v.u + 0x7fffu + ((v.u >> 16) & 1u)) >> 16;
    return (short)r;
}

__device__ __forceinline__ void stage16(const void* g, void* l) {
    typedef __attribute__((address_space(1))) const unsigned GA;
    typedef __attribute__((address_space(3))) unsigned LA;
    __builtin_amdgcn_global_load_lds((GA*)(const unsigned*)g, (LA*)(unsigned*)l, 16, 0, 0);
}

// ---------------------------------------------------------------------------
// Cast f32 [R][C] -> bf16 transposed [C][R]
// ---------------------------------------------------------------------------
__global__ __launch_bounds__(256) void transpose_cast_kernel(
        const float* __restrict__ in, short* __restrict__ out, int R, int C) {
    __shared__ float t[32][33];
    const int lx = threadIdx.x & 31;
    const int ly = threadIdx.x >> 5;
    const int r0 = blockIdx.x * 32;
    const int c0 = blockIdx.y * 32;
#pragma unroll
    for (int p = 0; p < 4; ++p)
        t[ly + 8 * p][lx] = in[(size_t)(r0 + ly + 8 * p) * C + c0 + lx];
    __syncthreads();
#pragma unroll
    for (int p = 0; p < 4; ++p)
        out[(size_t)(c0 + ly + 8 * p) * R + r0 + lx] = f2bf(t[lx][ly + 8 * p]);
}

// ---------------------------------------------------------------------------
// H = cast_bf16(F) @ W   using WT (bf16, [out][k]) ; H bf16 [NROWS][DIM]
// ---------------------------------------------------------------------------
__global__ __launch_bounds__(256) void gemm1_kernel(
        const float* __restrict__ F, const short* __restrict__ WT,
        short* __restrict__ H) {
    const int lane = threadIdx.x & 63;
    const int wid  = threadIdx.x >> 6;
    const int lr = lane & 15, lg = lane >> 4;
    const int r0 = blockIdx.x * 64 + wid * 16;
    const int c0 = blockIdx.y * 64;

    v4f acc[4] = {};
#pragma unroll
    for (int kc = 0; kc < 16; ++kc) {
        const int k = kc * 32 + lg * 8;
        const float* ap = F + (size_t)(r0 + lr) * DIM + k;
        float4 f0 = *(const float4*)ap;
        float4 f1 = *(const float4*)(ap + 4);
        v8s a;
        a[0] = f2bf(f0.x); a[1] = f2bf(f0.y); a[2] = f2bf(f0.z); a[3] = f2bf(f0.w);
        a[4] = f2bf(f1.x); a[5] = f2bf(f1.y); a[6] = f2bf(f1.z); a[7] = f2bf(f1.w);
#pragma unroll
        for (int ct = 0; ct < 4; ++ct) {
            v8s b = *(const v8s*)(WT + (size_t)(c0 + ct * 16 + lr) * DIM + k);
            acc[ct] = __builtin_amdgcn_mfma_f32_16x16x32_bf16(a, b, acc[ct], 0, 0, 0);
        }
    }
#pragma unroll
    for (int ct = 0; ct < 4; ++ct)
#pragma unroll
        for (int i = 0; i < 4; ++i)
            H[(size_t)(r0 + lg * 4 + i) * DIM + c0 + ct * 16 + lr] = f2bf(acc[ct][i]);
}

// ---------------------------------------------------------------------------
// Fused kernel, barrier-light schedule:
//   ring of 4 LDS chunk buffers = one full jt of Hs pre-staged
//   per jt: BAR(entry) -> [issue bF] -> phase A (pure LDS+MFMA, setprio) ->
//           relu/Sb writes -> LGKM0+BAR(mid) -> [issue stage for jt+1] ->
//           VMCNT(8) (bF ready, stage in flight) -> phase B (setprio) ->
//           VMCNT(0) (stage landed)
// ---------------------------------------------------------------------------
#define JSPLIT 4
#define JT_PER_BLOCK (NROWS / 64 / JSPLIT)   // 32 j-tiles of 64

__device__ __forceinline__ void stage_chunk(const short* __restrict__ Hs,
        short* buf, int j0, int cchunk, int wid, int lane) {
#pragma unroll
    for (int s = 0; s < 2; ++s) {
        const int L = ((wid * 2 + s) * 64 + lane) * 16;   // byte offset in 16KB chunk
        const int row = L >> 8;                            // 256B per row (128 bf16)
        const int p = L & 255;
        const int c = p ^ ((row & 7) << 4);                // inverse swizzle (involution)
        const char* g = (const char*)Hs + ((size_t)(j0 + row) << 10) + (cchunk << 8) + c;
        stage16(g, (char*)buf + L);
    }
}

__device__ __forceinline__ void compute_chunk(const short* buf, const v8s* afrag,
        int cchunk, int half, int lr, int lg, v4f& s0, v4f& s1) {
    const int xo = (lr & 7) << 4;   // swizzle term
#pragma unroll
    for (int kc = 0; kc < 4; ++kc) {
        const int col = kc * 64 + lg * 16;                // bytes within row
        const int r0 = half * 32 + lr;
        v8s hb0 = *(const v8s*)((const char*)buf + r0 * 256 + (col ^ xo));
        v8s hb1 = *(const v8s*)((const char*)buf + (r0 + 16) * 256 + (col ^ xo));
        s0 = __builtin_amdgcn_mfma_f32_16x16x32_bf16(afrag[cchunk * 4 + kc], hb0, s0, 0, 0, 0);
        s1 = __builtin_amdgcn_mfma_f32_16x16x32_bf16(afrag[cchunk * 4 + kc], hb1, s1, 0, 0, 0);
    }
}

__global__ __launch_bounds__(512, 2) void fused_kernel(
        const short* __restrict__ Hp, const short* __restrict__ Hs,
        const short* __restrict__ FsT, float* __restrict__ Cacc,
        float* __restrict__ ssq) {
    __shared__ __align__(16) short HsL[4][64][128];   // 4 x 16KB ring (one jt)
    __shared__ __align__(16) short Sb[64][72];        // S-tile bf16, padded rows

    const int lane = threadIdx.x & 63;
    const int wid  = threadIdx.x >> 6;
    const int lr = lane & 15, lg = lane >> 4;

    // XCD-aware swizzle: 512 blocks, 8 XCDs -> contiguous chunks of 64
    const int nwg = gridDim.x * gridDim.y;
    const int bid = blockIdx.x + gridDim.x * blockIdx.y;
    const int cpx = nwg >> 3;
    const int swz = (bid & 7) * cpx + (bid >> 3);
    const int bx = swz % gridDim.x;          // m-tile
    const int by = swz / gridDim.x;          // j-range

    const int m0    = bx * 64;
    const int strip = wid >> 1;
    const int half  = wid & 1;

    // Hp rows for phase A held in registers
    v8s afrag[16];
#pragma unroll
    for (int kc = 0; kc < 16; ++kc)
        afrag[kc] = *(const v8s*)(Hp + (size_t)(m0 + strip * 16 + lr) * DIM + kc * 32 + lg * 8);

    v4f accC[16] = {};
    float ssq_l = 0.f;

    const int jt0 = by * JT_PER_BLOCK;
    // prologue: stage all 4 chunks of jt0
#pragma unroll
    for (int cc = 0; cc < 4; ++cc)
        stage_chunk(Hs, &HsL[cc][0][0], jt0 * 64, cc, wid, lane);
    ASM_VMCNT(0);

    for (int jt = jt0; jt < jt0 + JT_PER_BLOCK; ++jt) {
        const int j = jt * 64;
        BAR;   // entry: ring for this jt complete (each wave's vmcnt(0)) & visible

        // issue bF (8 global->reg loads, consumed in phase B; hidden by phase A)
        v8s bF[8];
#pragma unroll
        for (int ct = 0; ct < 4; ++ct)
#pragma unroll
            for (int kc2 = 0; kc2 < 2; ++kc2)
                bF[ct * 2 + kc2] = *(const v8s*)(FsT +
                    (size_t)(wid * 64 + ct * 16 + lr) * NROWS + j + kc2 * 32 + lg * 8);

        // ---- phase A: pure LDS+MFMA, no internal barriers
        v4f s0 = {}, s1 = {};
        __builtin_amdgcn_s_setprio(1);
        compute_chunk(&HsL[0][0][0], afrag, 0, half, lr, lg, s0, s1);
        compute_chunk(&HsL[1][0][0], afrag, 1, half, lr, lg, s0, s1);
        compute_chunk(&HsL[2][0][0], afrag, 2, half, lr, lg, s0, s1);
        compute_chunk(&HsL[3][0][0], afrag, 3, half, lr, lg, s0, s1);
        __builtin_amdgcn_s_setprio(0);

        // ---- relu + ssq + S-tile to LDS (bf16)
#pragma unroll
        for (int i = 0; i < 4; ++i) {
            float v0 = fmaxf(s0[i], 0.f), v1 = fmaxf(s1[i], 0.f);
            ssq_l += v0 * v0 + v1 * v1;
            const int r = strip * 16 + lg * 4 + i;
            Sb[r][(half * 2 + 0) * 16 + lr] = f2bf(v0);
            Sb[r][(half * 2 + 1) * 16 + lr] = f2bf(v1);
        }
        ASM_LGKM0; BAR;   // mid: all ring reads done + Sb visible

        // ---- issue staging for next jt (safe: all waves past ring reads)
        const int jn = (jt + 1 < jt0 + JT_PER_BLOCK) ? (jt + 1) * 64 : jt0 * 64;
#pragma unroll
        for (int cc = 0; cc < 4; ++cc)
            stage_chunk(Hs, &HsL[cc][0][0], jn, cc, wid, lane);

        ASM_VMCNT(8);     // bF ready; stage (newer 8) stays in flight

        // ---- phase B: C[all rows][wid*64..+64] += S @ Fs
        __builtin_amdgcn_s_setprio(1);
#pragma unroll
        for (int kc2 = 0; kc2 < 2; ++kc2)
#pragma unroll
            for (int mt = 0; mt < 4; ++mt) {
                v8s aS = *(const v8s*)&Sb[mt * 16 + lr][kc2 * 32 + lg * 8];
#pragma unroll
                for (int ct = 0; ct < 4; ++ct)
                    accC[mt * 4 + ct] = __builtin_amdgcn_mfma_f32_16x16x32_bf16(
                        aS, bF[ct * 2 + kc2], accC[mt * 4 + ct], 0, 0, 0);
            }
        __builtin_amdgcn_s_setprio(0);

        ASM_VMCNT(0);     // own staging DMAs landed before next entry BAR
    }

    // ---- epilogue
    float w = ssq_l;
#pragma unroll
    for (int off = 32; off; off >>= 1) w += __shfl_down(w, off);
    if (lane == 0) atomicAdd(ssq, w);

#pragma unroll
    for (int mt = 0; mt < 4; ++mt)
#pragma unroll
        for (int ct = 0; ct < 4; ++ct)
#pragma unroll
            for (int i = 0; i < 4; ++i)
                atomicAdd(&Cacc[(size_t)(m0 + mt * 16 + lg * 4 + i) * DIM +
                                wid * 64 + ct * 16 + lr],
                          accC[mt * 4 + ct][i]);
}

// ---------------------------------------------------------------------------
__global__ __launch_bounds__(256) void scale_kernel(float* __restrict__ C,
                                                    const float* __restrict__ ssq) {
    const float rs = 1.0f / sqrtf(*ssq);
    const size_t i = (size_t)blockIdx.x * blockDim.x + threadIdx.x;
    float4* p = (float4*)C;
    float4 v = p[i];
    v.x *= rs; v.y *= rs; v.z *= rs; v.w *= rs;
    p[i] = v;
}

// ---------------------------------------------------------------------------
extern "C" void kernel_launch(void* const* d_in, const int* in_sizes, int n_in,
                              void* d_out, int out_size, void* d_ws, size_t ws_size,
                              hipStream_t stream) {
    const float* feat_p   = (const float*)d_in[0];
    const float* feat_s   = (const float*)d_in[1];
    const float* weight_a = (const float*)d_in[2];

    char* ws = (char*)d_ws;
    float* ssqp = (float*)ws;                                  // 4 B
    short* WT   = (short*)(ws + 512);                          // 512 KB
    short* Hp   = (short*)(ws + 512 + 524288);                 // 8 MB
    short* Hs   = (short*)(ws + 512 + 524288 + 8388608);       // 8 MB
    short* FsT  = (short*)(ws + 512 + 524288 + 16777216);      // 8 MB [DIM][NROWS]

    transpose_cast_kernel<<<dim3(DIM / 32, DIM / 32), 256, 0, stream>>>(weight_a, WT, DIM, DIM);
    transpose_cast_kernel<<<dim3(NROWS / 32, DIM / 32), 256, 0, stream>>>(feat_s, FsT, NROWS, DIM);

    gemm1_kernel<<<dim3(NROWS / 64, DIM / 64), 256, 0, stream>>>(feat_p, WT, Hp);
    gemm1_kernel<<<dim3(NROWS / 64, DIM / 64), 256, 0, stream>>>(feat_s, WT, Hs);

    hipMemsetAsync(d_out, 0, (size_t)out_size * sizeof(float), stream);
    hipMemsetAsync(ssqp, 0, sizeof(float), stream);

    fused_kernel<<<dim3(NROWS / 64, JSPLIT), 512, 0, stream>>>(Hp, Hs, FsT, (float*)d_out, ssqp);

    scale_kernel<<<(out_size / 4 + 255) / 256, 256, 0, stream>>>((float*)d_out, ssqp);
}